// Round 8
// baseline (98.992 us; speedup 1.0000x reference)
//
#include <hip/hip_runtime.h>

// x (N,D,L) f32, weight (K,D) f32, scale (1,) f32
// out (N,K,L) f32 = (||x||^2 + ||c||^2 - 2 x.c) / scale^2
#define N_ 32
#define D_ 128
#define L_ 3136
#define K_ 64

typedef _Float16 f16x8 __attribute__((ext_vector_type(8)));
typedef float    f32x4 __attribute__((ext_vector_type(4)));

// ---------------- prep: W -> fragment-ordered fp16 plane + ||c||^2 ----------------
// Fragment entry e = (dc*4+kt)*64 + lane holds 8 fp16:
//   W[kt*16 + (lane&15)][dc*32 + (lane>>4)*8 + j], j = 0..7
// = per-lane B-operand order for mfma_f32_16x16x32_f16.
__global__ __launch_bounds__(64) void prep_kernel(
    const float* __restrict__ w,
    unsigned short* __restrict__ wh,
    float* __restrict__ csq)
{
    const int b = blockIdx.x, lane = threadIdx.x;
    if (b < 16) {
        const int dc = b >> 2, kt = b & 3;
        const int row = kt * 16 + (lane & 15);
        const int d0  = dc * 32 + (lane >> 4) * 8;
        const float* src = w + row * D_ + d0;
        __attribute__((aligned(16))) unsigned short h[8];
#pragma unroll
        for (int j = 0; j < 8; ++j) {
            _Float16 v = (_Float16)src[j];              // RNE f32->f16
            h[j] = *(const unsigned short*)&v;
        }
        const size_t off = (size_t)(b * 64 + lane) * 8;
        *(ushort4*)(wh + off)     = *(const ushort4*)(h);
        *(ushort4*)(wh + off + 4) = *(const ushort4*)(h + 4);
    } else {           // block 16: ||c_k||^2 (fp32, exact)
        const float* wr = w + lane * D_;
        float s = 0.f;
#pragma unroll
        for (int d = 0; d < D_; d += 4) {
            float4 v = *(const float4*)(wr + d);
            s = fmaf(v.x, v.x, s); s = fmaf(v.y, v.y, s);
            s = fmaf(v.z, v.z, s); s = fmaf(v.w, v.w, s);
        }
        csq[lane] = s;
    }
}

// ---------------- main: 64 l x 64 k x one n per block ----------------
// KEY CHANGE vs R7: all 32 x-loads are issued BEFORE the LDS staging and the
// barrier, so the structural s_waitcnt vmcnt(0) at __syncthreads drains x and W
// in ONE latency exposure. Post-barrier loop is register/LDS-only (no vmem waits).
__global__ __launch_bounds__(256, 6) void enc_mfma_kernel(
    const float* __restrict__ x,
    const unsigned short* __restrict__ wh,
    const float* __restrict__ csqg,
    const float* __restrict__ scale,
    float* __restrict__ out)
{
    __shared__ __attribute__((aligned(16))) unsigned short lds_w[8192]; // 16 KB W frags
    __shared__ float lds_csq[K_];

    const int t    = threadIdx.x;
    const int wave = t >> 6;
    const int lane = t & 63;
    const int col  = lane & 15;
    const int quad = lane >> 4;
    const int n    = blockIdx.y;
    const int l0   = blockIdx.x * 64;

    // ---- (1) issue ALL x loads first: 32 coalesced dwords, no LDS dependence ----
    const float* xa = x + (size_t)n * D_ * L_ + l0 + wave * 16 + col;
    float xv[4][8];
#pragma unroll
    for (int dc = 0; dc < 4; ++dc) {
        const float* xp = xa + (size_t)(dc * 32 + quad * 8) * L_;
#pragma unroll
        for (int j = 0; j < 8; ++j) xv[dc][j] = xp[(size_t)j * L_];
    }

    // ---- (2) stage W frags (16 KB) + csq via global_load_lds (flat copy) ----
#pragma unroll
    for (int i = 0; i < 4; ++i) {
        const int c = wave * 4 + i;                        // chunk 0..15, wave-uniform
        __builtin_amdgcn_global_load_lds(
            (const __attribute__((address_space(1))) unsigned int*)(wh + (size_t)c * 512 + lane * 8),
            (__attribute__((address_space(3))) unsigned int*)&lds_w[c * 512],
            16, 0, 0);
    }
    if (wave == 0) {
        __builtin_amdgcn_global_load_lds(
            (const __attribute__((address_space(1))) unsigned int*)(csqg + lane),
            (__attribute__((address_space(3))) unsigned int*)lds_csq,
            4, 0, 0);
    }
    __syncthreads();   // ONE vmcnt(0) drain covers x regs + W staging

    // ---- (3) register/LDS-only MFMA loop ----
    f32x4 acc[4];
#pragma unroll
    for (int kt = 0; kt < 4; ++kt) acc[kt] = (f32x4){0.f, 0.f, 0.f, 0.f};
    float xsq = 0.f;

#pragma unroll
    for (int dc = 0; dc < 4; ++dc) {
        union { f16x8 v; _Float16 e[8]; } af;
#pragma unroll
        for (int j = 0; j < 8; ++j) {
            const float v = xv[dc][j];
            xsq = fmaf(v, v, xsq);             // exact fp32 ||x||^2
            af.e[j] = (_Float16)v;             // RNE f32->f16
        }
#pragma unroll
        for (int kt = 0; kt < 4; ++kt) {
            const int fo = ((dc * 4 + kt) * 64 + lane) * 8;  // lane-linear, conflict-free b128
            f16x8 bf = *(const f16x8*)&lds_w[fo];
            acc[kt] = __builtin_amdgcn_mfma_f32_16x16x32_f16(af.v, bf, acc[kt], 0, 0, 0);
        }
    }

    // ---- ||x||^2 reduce over quads; fetch the 4 cols this lane stores ----
    xsq += __shfl_xor(xsq, 16, 64);
    xsq += __shfl_xor(xsq, 32, 64);
    float xs[4];
#pragma unroll
    for (int r = 0; r < 4; ++r)
        xs[r] = __shfl(xsq, quad * 4 + r, 64); // xsq for col = quad*4+r

    // ---- epilogue: fuse terms, direct float4 stores from acc ----
    // D layout: col(lane&15)=k, row(quad*4+r)=l  => acc[kt] holds 4 consecutive l's
    const float sc = scale[0];
    const float inv_s2 = 1.0f / (sc * sc);
    float* op = out + (size_t)n * K_ * L_ + l0 + wave * 16 + quad * 4;
#pragma unroll
    for (int kt = 0; kt < 4; ++kt) {
        const float cs = lds_csq[kt * 16 + col];   // same-address across quads: broadcast
        float4 v;
        v.x = (xs[0] + cs - 2.0f * acc[kt][0]) * inv_s2;
        v.y = (xs[1] + cs - 2.0f * acc[kt][1]) * inv_s2;
        v.z = (xs[2] + cs - 2.0f * acc[kt][2]) * inv_s2;
        v.w = (xs[3] + cs - 2.0f * acc[kt][3]) * inv_s2;
        *(float4*)(op + (size_t)(kt * 16 + col) * L_) = v;
    }
}

extern "C" void kernel_launch(void* const* d_in, const int* in_sizes, int n_in,
                              void* d_out, int out_size, void* d_ws, size_t ws_size,
                              hipStream_t stream) {
    const float* x     = (const float*)d_in[0];
    const float* w     = (const float*)d_in[1];
    const float* scale = (const float*)d_in[2];
    float* out = (float*)d_out;

    // d_ws carve: [0,16K) W fp16 frags, [16K,+256) csq
    unsigned short* wh  = (unsigned short*)d_ws;
    float*          csq = (float*)((char*)d_ws + 16384);

    prep_kernel<<<17, 64, 0, stream>>>(w, wh, csq);
    dim3 grid(L_ / 64, N_);   // (49, 32) = 1568 blocks, no tail
    enc_mfma_kernel<<<grid, 256, 0, stream>>>(x, wh, csq, scale, out);
}